// Round 1
// baseline (312.441 us; speedup 1.0000x reference)
//
#include <hip/hip_runtime.h>
#include <hip/hip_bf16.h>

#define NN 4096
#define DD 512
#define HH 8
#define DH 64
#define BN 8192        // total rows (B*N)
#define PAIRS 16       // B*H

typedef unsigned int uint32;
typedef __attribute__((ext_vector_type(8))) short short8;
typedef __attribute__((ext_vector_type(4))) float f32x4;

__device__ __forceinline__ float blo(uint32 u) {
    union { uint32 i; float f; } c; c.i = u << 16; return c.f;
}
__device__ __forceinline__ unsigned short f2b(float x) {   // round-half-up to bf16
    union { float f; uint32 u; } c; c.f = x;
    return (unsigned short)((c.u + 0x8000u) >> 16);
}
__device__ __forceinline__ uint32 pack2(float lo, float hi) {
    return (uint32)f2b(lo) | ((uint32)f2b(hi) << 16);
}
__device__ __forceinline__ uint32 cvtpk(float lo, float hi) {  // packed bf16 pair, RNE
    uint32 r;
    asm("v_cvt_pk_bf16_f32 %0, %1, %2" : "=v"(r) : "v"(lo), "v"(hi));
    return r;
}
// exp(s/8) with overflow clamp, as a single mul + v_exp
__device__ __forceinline__ float expsc(float s) {
    return __builtin_amdgcn_exp2f(fminf(s * 0.18033688011112042f, 86.5f));
}

// ---------------------------------------------------------------------------
// Kernel 0: dtype probe (verified working in rounds 2-3).
// ---------------------------------------------------------------------------
__global__ void detect_dtype(const uint32* __restrict__ xw, uint32* __restrict__ flag) {
    __shared__ int cnt;
    if (threadIdx.x == 0) cnt = 0;
    __syncthreads();
    int c = 0;
    for (int i = threadIdx.x; i < 1024; i += 64) {
        uint32 e = (xw[i] >> 7) & 0xFFu;
        if (e >= 110u && e <= 135u) c++;
    }
    atomicAdd(&cnt, c);
    __syncthreads();
    if (threadIdx.x == 0) *flag = (cnt < 512) ? 1u : 0u;
}

// ---------------------------------------------------------------------------
// Convert kernels (unchanged).
// ---------------------------------------------------------------------------
__global__ __launch_bounds__(256) void conv_x(const void* __restrict__ src,
                                              unsigned short* __restrict__ dst,
                                              const uint32* __restrict__ flagp) {
    int i0 = (blockIdx.x * 256 + threadIdx.x) * 8;
    if (*flagp) {
        const float4* s = (const float4*)src;
        float4 a = s[i0 >> 2], b = s[(i0 >> 2) + 1];
        uint4 o;
        o.x = pack2(a.x, a.y); o.y = pack2(a.z, a.w);
        o.z = pack2(b.x, b.y); o.w = pack2(b.z, b.w);
        *(uint4*)(dst + i0) = o;
    } else {
        *(uint4*)(dst + i0) = ((const uint4*)src)[i0 >> 3];
    }
}

__global__ __launch_bounds__(256) void conv_w(const void* s0, const void* s1,
                                              const void* s2, const void* s3,
                                              unsigned short* __restrict__ dst,
                                              const uint32* __restrict__ flagp) {
    int seg = blockIdx.x >> 7;
    const void* src = (seg == 0) ? s0 : (seg == 1) ? s1 : (seg == 2) ? s2 : s3;
    unsigned short* d = dst + (size_t)seg * DD * DD;
    int i0 = ((blockIdx.x & 127) * 256 + threadIdx.x) * 8;
    if (*flagp) {
        const float4* s = (const float4*)src;
        float4 a = s[i0 >> 2], b = s[(i0 >> 2) + 1];
        uint4 o;
        o.x = pack2(a.x, a.y); o.y = pack2(a.z, a.w);
        o.z = pack2(b.x, b.y); o.w = pack2(b.z, b.w);
        *(uint4*)(d + i0) = o;
    } else {
        *(uint4*)(d + i0) = ((const uint4*)src)[i0 >> 3];
    }
}

__global__ __launch_bounds__(256) void conv_b(const void* s0, const void* s1,
                                              const void* s2, const void* s3,
                                              float* __restrict__ dst,
                                              const uint32* __restrict__ flagp) {
    const void* sl[4] = { s0, s1, s2, s3 };
    int fp32mode = (int)*flagp;
    #pragma unroll
    for (int m = 0; m < 4; ++m) {
        #pragma unroll
        for (int j = 0; j < 2; ++j) {
            int i = threadIdx.x * 2 + j;
            float v;
            if (fp32mode) v = ((const float*)sl[m])[i];
            else {
                union { uint32 u; float f; } c;
                c.u = ((uint32)((const unsigned short*)sl[m])[i]) << 16;
                v = c.f;
            }
            dst[m * DD + i] = v;
        }
    }
}

// ---------------------------------------------------------------------------
// QKV projection GEMM (unchanged this round).
// ---------------------------------------------------------------------------
__global__ __launch_bounds__(256) void qkv_gemm(
    const unsigned short* __restrict__ xb,
    const unsigned short* __restrict__ wsb,
    const float* __restrict__ bsf,
    unsigned short* __restrict__ Qb, unsigned short* __restrict__ Kb,
    unsigned short* __restrict__ VTg)
{
    __shared__ unsigned short As[128 * 40];
    __shared__ unsigned short Bs[128 * 40];
    const int tid = threadIdx.x;
    const int mat = blockIdx.x >> 8;
    const int rem = blockIdx.x & 255;
    const int nt = rem >> 6, mt = rem & 63;
    const int m0 = mt * 128, n0 = nt * 128;
    const int w = tid >> 6, lane = tid & 63, quad = lane >> 4, col = lane & 15;
    const int wr = w >> 1, wc = w & 1;
    const unsigned short* wm = wsb + (size_t)mat * DD * DD;
    const bool qk = (mat < 2);

    f32x4 acc[4][4];
    #pragma unroll
    for (int i = 0; i < 4; ++i)
        #pragma unroll
        for (int j = 0; j < 4; ++j)
            acc[i][j] = (f32x4){0.f, 0.f, 0.f, 0.f};

    for (int kt = 0; kt < 16; ++kt) {
        int k0 = kt * 32;
        __syncthreads();
        #pragma unroll
        for (int it = 0; it < 2; ++it) {
            int idx = tid + it * 256;
            int row = idx >> 2, c4 = idx & 3;
            *(uint4*)&As[row * 40 + c4 * 8] =
                *(const uint4*)(xb + (size_t)(m0 + row) * DD + k0 + c4 * 8);
            *(uint4*)&Bs[row * 40 + c4 * 8] =
                *(const uint4*)(wm + (size_t)(n0 + row) * DD + k0 + c4 * 8);
        }
        __syncthreads();
        if (qk) {
            short8 wf[4], xf[4];
            #pragma unroll
            for (int i = 0; i < 4; ++i)
                wf[i] = *(const short8*)&Bs[(wr * 64 + i * 16 + col) * 40 + quad * 8];
            #pragma unroll
            for (int j = 0; j < 4; ++j)
                xf[j] = *(const short8*)&As[(wc * 64 + j * 16 + col) * 40 + quad * 8];
            #pragma unroll
            for (int i = 0; i < 4; ++i)
                #pragma unroll
                for (int j = 0; j < 4; ++j)
                    acc[i][j] = __builtin_amdgcn_mfma_f32_16x16x32_bf16(
                        wf[i], xf[j], acc[i][j], 0, 0, 0);
        } else {
            short8 xf[4], wf[4];
            #pragma unroll
            for (int i = 0; i < 4; ++i)
                xf[i] = *(const short8*)&As[(wr * 64 + i * 16 + col) * 40 + quad * 8];
            #pragma unroll
            for (int j = 0; j < 4; ++j)
                wf[j] = *(const short8*)&Bs[(wc * 64 + j * 16 + col) * 40 + quad * 8];
            #pragma unroll
            for (int i = 0; i < 4; ++i)
                #pragma unroll
                for (int j = 0; j < 4; ++j)
                    acc[i][j] = __builtin_amdgcn_mfma_f32_16x16x32_bf16(
                        xf[i], wf[j], acc[i][j], 0, 0, 0);
        }
    }

    if (qk) {
        unsigned short* Om = (mat == 0) ? Qb : Kb;
        #pragma unroll
        for (int i = 0; i < 4; ++i) {
            int e0 = n0 + wr * 64 + i * 16 + quad * 4;
            float4 bj = *(const float4*)(bsf + mat * DD + e0);
            int h = e0 >> 6, jj0 = e0 & 63;
            #pragma unroll
            for (int j = 0; j < 4; ++j) {
                int g = m0 + wc * 64 + j * 16 + col;
                int b = g >> 12, n = g & (NN - 1);
                uint32 lo = pack2(acc[i][j][0] + bj.x, acc[i][j][1] + bj.y);
                uint32 hi = pack2(acc[i][j][2] + bj.z, acc[i][j][3] + bj.w);
                uint2 v; v.x = lo; v.y = hi;
                *(uint2*)(Om + ((size_t)((b << 3) + h) * NN + n) * DH + jj0) = v;
            }
        }
    } else {
        #pragma unroll
        for (int j = 0; j < 4; ++j) {
            int e = n0 + wc * 64 + j * 16 + col;
            float bj = bsf[2 * DD + e];
            int h = e >> 6, jj = e & 63;
            #pragma unroll
            for (int i = 0; i < 4; ++i) {
                int g0 = m0 + wr * 64 + i * 16 + quad * 4;
                int b = g0 >> 12, n = g0 & (NN - 1);
                uint32 lo = pack2(acc[i][j][0] + bj, acc[i][j][1] + bj);
                uint32 hi = pack2(acc[i][j][2] + bj, acc[i][j][3] + bj);
                uint2 v; v.x = lo; v.y = hi;
                *(uint2*)(VTg + ((size_t)((b << 3) + h) * DH + jj) * NN + n) = v;
            }
        }
    }
}

// ---------------------------------------------------------------------------
// MFMA flash attention v3:
//   - KVBLK=128 (32 iters): half the barriers/staging round-trips of v2.
//     LDS 70.6 KB/block is free: grid (512 blocks) caps us at 2 blocks/CU.
//   - async-STAGE split (T14): next tile's K/V global loads are issued right
//     after the barrier; consumed by next iteration's ds_write, so HBM/L2
//     latency hides under QK^T + softmax + PV.
//   - P packing via v_cvt_pk_bf16_f32 (1 instr/pair vs ~6 for manual pack2).
//   - exp folded to one v_mul + v_exp (exp2 with pre-scaled log2e).
// Same S^T orientation + same-wave Pt roundtrip (no barrier) as v2.
// ---------------------------------------------------------------------------
__global__ __launch_bounds__(512, 4) void attn_mfma(
    const unsigned short* __restrict__ Qb,
    const unsigned short* __restrict__ Kb,
    const unsigned short* __restrict__ VTg,
    unsigned short* __restrict__ Ob)
{
    __shared__ unsigned short Kt[128 * 72];    // [key][dim],  pad 64->72
    __shared__ unsigned short Vt[64 * 136];    // [dim][key],  pad 128->136
    __shared__ unsigned short Pt[128 * 136];   // [qrow][key], pad 128->136

    const int tid  = threadIdx.x;
    const int w    = tid >> 6;
    const int lane = tid & 63;
    const int quad = lane >> 4;
    const int col  = lane & 15;
    const int pair = blockIdx.x >> 5;
    const int chunk = blockIdx.x & 31;
    const size_t base = (size_t)pair * NN;
    const int n0 = chunk * 128;
    const int qbase = w * 16;

    // Q A-fragments for this wave's 16 rows: lane&15 = qrow, regs = dim
    short8 qf[2];
    #pragma unroll
    for (int kk = 0; kk < 2; ++kk)
        qf[kk] = *(const short8*)(Qb +
            (base + n0 + qbase + col) * DH + kk * 32 + quad * 8);

    f32x4 accO[4];
    #pragma unroll
    for (int tc = 0; tc < 4; ++tc) accO[tc] = (f32x4){0.f, 0.f, 0.f, 0.f};
    float lsum = 0.f;

    // staging: K tile 128x64 (2 rounds of 512x16B), V tile 64x128 (2 rounds)
    const int krow = tid >> 3, kc8 = (tid & 7) * 8;
    const int vrow = tid >> 4, vc8 = (tid & 15) * 8;
    const unsigned short* Kg = Kb + base * DH;
    const unsigned short* Vg = VTg + (size_t)pair * DH * NN;
    const int prow = (qbase + col) * 136;

    uint4 kreg[2], vreg[2];
    #pragma unroll
    for (int r = 0; r < 2; ++r) {
        kreg[r] = *(const uint4*)(Kg + (size_t)(krow + r * 64) * DH + kc8);
        vreg[r] = *(const uint4*)(Vg + (size_t)(vrow + r * 32) * NN + vc8);
    }

    for (int kt = 0; kt < NN / 128; ++kt) {
        __syncthreads();                      // prior iter's LDS reads done
        #pragma unroll
        for (int r = 0; r < 2; ++r) {
            *(uint4*)&Kt[(krow + r * 64) * 72 + kc8] = kreg[r];
            *(uint4*)&Vt[(vrow + r * 32) * 136 + vc8] = vreg[r];
        }
        __syncthreads();                      // tile visible

        // issue next tile's loads now; waited on at next iter's ds_write
        int ktn = (kt + 1 < NN / 128) ? kt + 1 : kt;
        #pragma unroll
        for (int r = 0; r < 2; ++r) {
            kreg[r] = *(const uint4*)(Kg + (size_t)(ktn * 128 + krow + r * 64) * DH + kc8);
            vreg[r] = *(const uint4*)(Vg + (size_t)(vrow + r * 32) * NN + ktn * 128 + vc8);
        }

        // S^T = K Q^T : D[m=key][n=qrow]; C-layout: col=qrow, regs=key
        f32x4 s[8];
        #pragma unroll
        for (int tc = 0; tc < 8; ++tc) s[tc] = (f32x4){0.f, 0.f, 0.f, 0.f};
        #pragma unroll
        for (int tc = 0; tc < 8; ++tc) {
            #pragma unroll
            for (int kk = 0; kk < 2; ++kk) {
                short8 kf = *(const short8*)&Kt[(tc * 16 + col) * 72 + kk * 32 + quad * 8];
                s[tc] = __builtin_amdgcn_mfma_f32_16x16x32_bf16(kf, qf[kk], s[tc], 0, 0, 0);
            }
        }

        // p = exp(s/8); packed b64 write to Pt[qrow][key] (keys consecutive)
        #pragma unroll
        for (int tc = 0; tc < 8; ++tc) {
            float p0 = expsc(s[tc][0]);
            float p1 = expsc(s[tc][1]);
            float p2 = expsc(s[tc][2]);
            float p3 = expsc(s[tc][3]);
            lsum += (p0 + p1) + (p2 + p3);
            uint2 v; v.x = cvtpk(p0, p1); v.y = cvtpk(p2, p3);
            *(uint2*)&Pt[prow + tc * 16 + quad * 4] = v;
        }

        // read P back as A-frags (same wave's rows; no barrier needed)
        short8 pf[4];
        #pragma unroll
        for (int ks = 0; ks < 4; ++ks)
            pf[ks] = *(const short8*)&Pt[prow + ks * 32 + quad * 8];

        // O += P V : A=P[m=qrow][k=key], B=V^T rows [n=dim][k=key]
        #pragma unroll
        for (int tc = 0; tc < 4; ++tc) {
            #pragma unroll
            for (int ks = 0; ks < 4; ++ks) {
                short8 vf = *(const short8*)&Vt[(tc * 16 + col) * 136 + ks * 32 + quad * 8];
                accO[tc] = __builtin_amdgcn_mfma_f32_16x16x32_bf16(pf[ks], vf, accO[tc], 0, 0, 0);
            }
        }
    }

    // reduce rowsums across quads: after this, lane holds l[qrow = lane&15]
    lsum += __shfl_xor(lsum, 16);
    lsum += __shfl_xor(lsum, 32);

    // epilogue: need l for qrow = quad*4+r
    float inv[4];
    #pragma unroll
    for (int r = 0; r < 4; ++r)
        inv[r] = 1.f / __shfl(lsum, quad * 4 + r);

    #pragma unroll
    for (int tc = 0; tc < 4; ++tc)
        #pragma unroll
        for (int r = 0; r < 4; ++r) {
            float v = accO[tc][r] * inv[r];
            Ob[(base + n0 + qbase + quad * 4 + r) * DH + tc * 16 + col] = f2b(v);
        }
}

// ---------------------------------------------------------------------------
// Output projection GEMM (unchanged this round).
// ---------------------------------------------------------------------------
__global__ __launch_bounds__(256) void out_gemm(
    const unsigned short* __restrict__ Ob,
    const unsigned short* __restrict__ wob,
    const float* __restrict__ bof,
    const uint32* __restrict__ flagp,
    void* __restrict__ outp)
{
    __shared__ unsigned short As[128 * 40];
    __shared__ unsigned short Bs[128 * 40];
    const int tid = threadIdx.x;
    const int nt = blockIdx.x >> 6, mt = blockIdx.x & 63;
    const int m0 = mt * 128, n0 = nt * 128;
    const int w = tid >> 6, lane = tid & 63, quad = lane >> 4, col = lane & 15;
    const int wr = w >> 1, wc = w & 1;
    const int fp32mode = (int)*flagp;

    f32x4 acc[4][4];
    #pragma unroll
    for (int i = 0; i < 4; ++i)
        #pragma unroll
        for (int j = 0; j < 4; ++j)
            acc[i][j] = (f32x4){0.f, 0.f, 0.f, 0.f};

    for (int kt = 0; kt < 16; ++kt) {
        int k0 = kt * 32;
        int h = k0 >> 6, koff = k0 & 63;
        __syncthreads();
        #pragma unroll
        for (int it = 0; it < 2; ++it) {
            int idx = tid + it * 256;
            int row = idx >> 2, c4 = idx & 3;
            int g = m0 + row, b = g >> 12, n = g & (NN - 1);
            *(uint4*)&As[row * 40 + c4 * 8] = *(const uint4*)(Ob +
                ((size_t)((b << 3) + h) * NN + n) * DH + koff + c4 * 8);
            *(uint4*)&Bs[row * 40 + c4 * 8] =
                *(const uint4*)(wob + (size_t)(n0 + row) * DD + k0 + c4 * 8);
        }
        __syncthreads();
        short8 wf[4], yf[4];
        #pragma unroll
        for (int i = 0; i < 4; ++i)
            wf[i] = *(const short8*)&Bs[(wr * 64 + i * 16 + col) * 40 + quad * 8];
        #pragma unroll
        for (int j = 0; j < 4; ++j)
            yf[j] = *(const short8*)&As[(wc * 64 + j * 16 + col) * 40 + quad * 8];
        #pragma unroll
        for (int i = 0; i < 4; ++i)
            #pragma unroll
            for (int j = 0; j < 4; ++j)
                acc[i][j] = __builtin_amdgcn_mfma_f32_16x16x32_bf16(
                    wf[i], yf[j], acc[i][j], 0, 0, 0);
    }

    #pragma unroll
    for (int i = 0; i < 4; ++i) {
        int e0 = n0 + wr * 64 + i * 16 + quad * 4;
        float4 bj = *(const float4*)(bof + e0);
        #pragma unroll
        for (int j = 0; j < 4; ++j) {
            int g = m0 + wc * 64 + j * 16 + col;
            float v0 = acc[i][j][0] + bj.x;
            float v1 = acc[i][j][1] + bj.y;
            float v2 = acc[i][j][2] + bj.z;
            float v3 = acc[i][j][3] + bj.w;
            if (fp32mode) {
                float4 o; o.x = v0; o.y = v1; o.z = v2; o.w = v3;
                *(float4*)((float*)outp + (size_t)g * DD + e0) = o;
            } else {
                uint2 o; o.x = pack2(v0, v1); o.y = pack2(v2, v3);
                *(uint2*)((unsigned short*)outp + (size_t)g * DD + e0) = o;
            }
        }
    }
}

// ---------------------------------------------------------------------------
extern "C" void kernel_launch(void* const* d_in, const int* in_sizes, int n_in,
                              void* d_out, int out_size, void* d_ws, size_t ws_size,
                              hipStream_t stream) {
    char* p = (char*)d_ws;
    uint32* flag = (uint32*)p;                  p += 256;
    unsigned short* xb  = (unsigned short*)p;   p += (size_t)BN * DD * 2;
    unsigned short* wsb = (unsigned short*)p;   p += (size_t)4 * DD * DD * 2;
    float*          bsf = (float*)p;            p += (size_t)4 * DD * 4;
    unsigned short* Qb  = (unsigned short*)p;   p += (size_t)PAIRS * NN * DH * 2;
    unsigned short* Kb  = (unsigned short*)p;   p += (size_t)PAIRS * NN * DH * 2;
    unsigned short* VTg = (unsigned short*)p;   p += (size_t)PAIRS * NN * DH * 2;
    unsigned short* Ob  = (unsigned short*)p;   p += (size_t)PAIRS * NN * DH * 2;

    detect_dtype<<<1, 64, 0, stream>>>((const uint32*)d_in[0], flag);
    conv_x<<<BN * DD / 2048, 256, 0, stream>>>(d_in[0], xb, flag);
    conv_w<<<512, 256, 0, stream>>>(d_in[1], d_in[3], d_in[5], d_in[7], wsb, flag);
    conv_b<<<1, 256, 0, stream>>>(d_in[2], d_in[4], d_in[6], d_in[8], bsf, flag);
    qkv_gemm<<<768, 256, 0, stream>>>(xb, wsb, bsf, Qb, Kb, VTg);
    attn_mfma<<<PAIRS * 32, 512, 0, stream>>>(Qb, Kb, VTg, Ob);
    out_gemm<<<256, 256, 0, stream>>>(Ob, wsb + (size_t)3 * DD * DD,
                                      bsf + 3 * DD, flag, d_out);
}

// Round 2
// 249.474 us; speedup vs baseline: 1.2524x; 1.2524x over previous
//
#include <hip/hip_runtime.h>
#include <hip/hip_bf16.h>

#define NN 4096
#define DD 512
#define HH 8
#define DH 64
#define BN 8192        // total rows (B*N)
#define PAIRS 16       // B*H

typedef unsigned int uint32;
typedef __attribute__((ext_vector_type(8))) short short8;
typedef __attribute__((ext_vector_type(4))) float f32x4;

__device__ __forceinline__ float blo(uint32 u) {
    union { uint32 i; float f; } c; c.i = u << 16; return c.f;
}
__device__ __forceinline__ unsigned short f2b(float x) {   // round-half-up to bf16
    union { float f; uint32 u; } c; c.f = x;
    return (unsigned short)((c.u + 0x8000u) >> 16);
}
__device__ __forceinline__ uint32 pack2(float lo, float hi) {
    return (uint32)f2b(lo) | ((uint32)f2b(hi) << 16);
}
__device__ __forceinline__ uint32 cvtpk(float lo, float hi) {  // packed bf16 pair, RNE
    uint32 r;
    asm("v_cvt_pk_bf16_f32 %0, %1, %2" : "=v"(r) : "v"(lo), "v"(hi));
    return r;
}
// softmax scale (1/8 * log2e) is pre-folded into Q by qkv_gemm; here just clamp+exp2
__device__ __forceinline__ float expsc(float s) {
    return __builtin_amdgcn_exp2f(fminf(s, 86.5f));
}
#define QSCALE 0.18033688011112042f   // log2(e)/8

// ---------------------------------------------------------------------------
// Kernel 0: dtype probe (verified working in rounds 2-3).
// ---------------------------------------------------------------------------
__global__ void detect_dtype(const uint32* __restrict__ xw, uint32* __restrict__ flag) {
    __shared__ int cnt;
    if (threadIdx.x == 0) cnt = 0;
    __syncthreads();
    int c = 0;
    for (int i = threadIdx.x; i < 1024; i += 64) {
        uint32 e = (xw[i] >> 7) & 0xFFu;
        if (e >= 110u && e <= 135u) c++;
    }
    atomicAdd(&cnt, c);
    __syncthreads();
    if (threadIdx.x == 0) *flag = (cnt < 512) ? 1u : 0u;
}

// ---------------------------------------------------------------------------
// Convert kernels (unchanged).
// ---------------------------------------------------------------------------
__global__ __launch_bounds__(256) void conv_x(const void* __restrict__ src,
                                              unsigned short* __restrict__ dst,
                                              const uint32* __restrict__ flagp) {
    int i0 = (blockIdx.x * 256 + threadIdx.x) * 8;
    if (*flagp) {
        const float4* s = (const float4*)src;
        float4 a = s[i0 >> 2], b = s[(i0 >> 2) + 1];
        uint4 o;
        o.x = pack2(a.x, a.y); o.y = pack2(a.z, a.w);
        o.z = pack2(b.x, b.y); o.w = pack2(b.z, b.w);
        *(uint4*)(dst + i0) = o;
    } else {
        *(uint4*)(dst + i0) = ((const uint4*)src)[i0 >> 3];
    }
}

__global__ __launch_bounds__(256) void conv_w(const void* s0, const void* s1,
                                              const void* s2, const void* s3,
                                              unsigned short* __restrict__ dst,
                                              const uint32* __restrict__ flagp) {
    int seg = blockIdx.x >> 7;
    const void* src = (seg == 0) ? s0 : (seg == 1) ? s1 : (seg == 2) ? s2 : s3;
    unsigned short* d = dst + (size_t)seg * DD * DD;
    int i0 = ((blockIdx.x & 127) * 256 + threadIdx.x) * 8;
    if (*flagp) {
        const float4* s = (const float4*)src;
        float4 a = s[i0 >> 2], b = s[(i0 >> 2) + 1];
        uint4 o;
        o.x = pack2(a.x, a.y); o.y = pack2(a.z, a.w);
        o.z = pack2(b.x, b.y); o.w = pack2(b.z, b.w);
        *(uint4*)(d + i0) = o;
    } else {
        *(uint4*)(d + i0) = ((const uint4*)src)[i0 >> 3];
    }
}

__global__ __launch_bounds__(256) void conv_b(const void* s0, const void* s1,
                                              const void* s2, const void* s3,
                                              float* __restrict__ dst,
                                              const uint32* __restrict__ flagp) {
    const void* sl[4] = { s0, s1, s2, s3 };
    int fp32mode = (int)*flagp;
    #pragma unroll
    for (int m = 0; m < 4; ++m) {
        #pragma unroll
        for (int j = 0; j < 2; ++j) {
            int i = threadIdx.x * 2 + j;
            float v;
            if (fp32mode) v = ((const float*)sl[m])[i];
            else {
                union { uint32 u; float f; } c;
                c.u = ((uint32)((const unsigned short*)sl[m])[i]) << 16;
                v = c.f;
            }
            dst[m * DD + i] = v;
        }
    }
}

// ---------------------------------------------------------------------------
// QKV projection GEMM. Q output is pre-scaled by log2(e)/8 so attention's
// softmax needs only min+exp2 per score.
// ---------------------------------------------------------------------------
__global__ __launch_bounds__(256) void qkv_gemm(
    const unsigned short* __restrict__ xb,
    const unsigned short* __restrict__ wsb,
    const float* __restrict__ bsf,
    unsigned short* __restrict__ Qb, unsigned short* __restrict__ Kb,
    unsigned short* __restrict__ VTg)
{
    __shared__ unsigned short As[128 * 40];
    __shared__ unsigned short Bs[128 * 40];
    const int tid = threadIdx.x;
    const int mat = blockIdx.x >> 8;
    const int rem = blockIdx.x & 255;
    const int nt = rem >> 6, mt = rem & 63;
    const int m0 = mt * 128, n0 = nt * 128;
    const int w = tid >> 6, lane = tid & 63, quad = lane >> 4, col = lane & 15;
    const int wr = w >> 1, wc = w & 1;
    const unsigned short* wm = wsb + (size_t)mat * DD * DD;
    const bool qk = (mat < 2);

    f32x4 acc[4][4];
    #pragma unroll
    for (int i = 0; i < 4; ++i)
        #pragma unroll
        for (int j = 0; j < 4; ++j)
            acc[i][j] = (f32x4){0.f, 0.f, 0.f, 0.f};

    for (int kt = 0; kt < 16; ++kt) {
        int k0 = kt * 32;
        __syncthreads();
        #pragma unroll
        for (int it = 0; it < 2; ++it) {
            int idx = tid + it * 256;
            int row = idx >> 2, c4 = idx & 3;
            *(uint4*)&As[row * 40 + c4 * 8] =
                *(const uint4*)(xb + (size_t)(m0 + row) * DD + k0 + c4 * 8);
            *(uint4*)&Bs[row * 40 + c4 * 8] =
                *(const uint4*)(wm + (size_t)(n0 + row) * DD + k0 + c4 * 8);
        }
        __syncthreads();
        if (qk) {
            short8 wf[4], xf[4];
            #pragma unroll
            for (int i = 0; i < 4; ++i)
                wf[i] = *(const short8*)&Bs[(wr * 64 + i * 16 + col) * 40 + quad * 8];
            #pragma unroll
            for (int j = 0; j < 4; ++j)
                xf[j] = *(const short8*)&As[(wc * 64 + j * 16 + col) * 40 + quad * 8];
            #pragma unroll
            for (int i = 0; i < 4; ++i)
                #pragma unroll
                for (int j = 0; j < 4; ++j)
                    acc[i][j] = __builtin_amdgcn_mfma_f32_16x16x32_bf16(
                        wf[i], xf[j], acc[i][j], 0, 0, 0);
        } else {
            short8 xf[4], wf[4];
            #pragma unroll
            for (int i = 0; i < 4; ++i)
                xf[i] = *(const short8*)&As[(wr * 64 + i * 16 + col) * 40 + quad * 8];
            #pragma unroll
            for (int j = 0; j < 4; ++j)
                wf[j] = *(const short8*)&Bs[(wc * 64 + j * 16 + col) * 40 + quad * 8];
            #pragma unroll
            for (int i = 0; i < 4; ++i)
                #pragma unroll
                for (int j = 0; j < 4; ++j)
                    acc[i][j] = __builtin_amdgcn_mfma_f32_16x16x32_bf16(
                        xf[i], wf[j], acc[i][j], 0, 0, 0);
        }
    }

    if (qk) {
        unsigned short* Om = (mat == 0) ? Qb : Kb;
        const float qs = (mat == 0) ? QSCALE : 1.0f;
        #pragma unroll
        for (int i = 0; i < 4; ++i) {
            int e0 = n0 + wr * 64 + i * 16 + quad * 4;
            float4 bj = *(const float4*)(bsf + mat * DD + e0);
            int h = e0 >> 6, jj0 = e0 & 63;
            #pragma unroll
            for (int j = 0; j < 4; ++j) {
                int g = m0 + wc * 64 + j * 16 + col;
                int b = g >> 12, n = g & (NN - 1);
                uint32 lo = pack2((acc[i][j][0] + bj.x) * qs, (acc[i][j][1] + bj.y) * qs);
                uint32 hi = pack2((acc[i][j][2] + bj.z) * qs, (acc[i][j][3] + bj.w) * qs);
                uint2 v; v.x = lo; v.y = hi;
                *(uint2*)(Om + ((size_t)((b << 3) + h) * NN + n) * DH + jj0) = v;
            }
        }
    } else {
        #pragma unroll
        for (int j = 0; j < 4; ++j) {
            int e = n0 + wc * 64 + j * 16 + col;
            float bj = bsf[2 * DD + e];
            int h = e >> 6, jj = e & 63;
            #pragma unroll
            for (int i = 0; i < 4; ++i) {
                int g0 = m0 + wr * 64 + i * 16 + quad * 4;
                int b = g0 >> 12, n = g0 & (NN - 1);
                uint32 lo = pack2(acc[i][j][0] + bj, acc[i][j][1] + bj);
                uint32 hi = pack2(acc[i][j][2] + bj, acc[i][j][3] + bj);
                uint2 v; v.x = lo; v.y = hi;
                *(uint2*)(VTg + ((size_t)((b << 3) + h) * DH + jj) * NN + n) = v;
            }
        }
    }
}

// ---------------------------------------------------------------------------
// MFMA flash attention v4: KVBLK=64 (register-light: no spill), K/V LDS
// double-buffered so only ONE barrier per iteration; next tile prefetched
// into 2 uint4 regs right after the ds_write (latency hides under compute,
// regs recycled immediately). cvt_pk P-packing, pre-scaled Q (min+exp2
// softmax), setprio around MFMA clusters.
// ---------------------------------------------------------------------------
__global__ __launch_bounds__(512, 4) void attn_mfma(
    const unsigned short* __restrict__ Qb,
    const unsigned short* __restrict__ Kb,
    const unsigned short* __restrict__ VTg,
    unsigned short* __restrict__ Ob)
{
    __shared__ unsigned short Kt[2][64 * 72];    // [key][dim],  pad 64->72
    __shared__ unsigned short Vt[2][64 * 72];    // [dim][key],  pad 64->72
    __shared__ unsigned short Pt[128 * 72];      // [qrow][key], pad 64->72

    const int tid  = threadIdx.x;
    const int w    = tid >> 6;
    const int lane = tid & 63;
    const int quad = lane >> 4;
    const int col  = lane & 15;
    const int pair = blockIdx.x >> 5;
    const int chunk = blockIdx.x & 31;
    const size_t base = (size_t)pair * NN;
    const int n0 = chunk * 128;
    const int qbase = w * 16;

    // Q A/B-fragments for this wave's 16 rows: lane&15 = qrow, regs = dim
    short8 qf[2];
    #pragma unroll
    for (int kk = 0; kk < 2; ++kk)
        qf[kk] = *(const short8*)(Qb +
            (base + n0 + qbase + col) * DH + kk * 32 + quad * 8);

    f32x4 accO[4];
    #pragma unroll
    for (int tc = 0; tc < 4; ++tc) accO[tc] = (f32x4){0.f, 0.f, 0.f, 0.f};
    float lsum = 0.f;

    const int skey = tid >> 3;      // 0..63 (key for K stage, dim for V stage)
    const int sc8  = (tid & 7) * 8;
    const unsigned short* Kg = Kb + base * DH;
    const unsigned short* Vg = VTg + (size_t)pair * DH * NN;
    const int prow = (qbase + col) * 72;

    // prologue: tile 0 -> LDS buf0; tile 1 -> regs
    uint4 kreg = *(const uint4*)(Kg + (size_t)skey * DH + sc8);
    uint4 vreg = *(const uint4*)(Vg + (size_t)skey * NN + sc8);
    *(uint4*)&Kt[0][skey * 72 + sc8] = kreg;
    *(uint4*)&Vt[0][skey * 72 + sc8] = vreg;
    kreg = *(const uint4*)(Kg + (size_t)(64 + skey) * DH + sc8);
    vreg = *(const uint4*)(Vg + (size_t)skey * NN + 64 + sc8);
    __syncthreads();

    for (int kt = 0; kt < NN / 64; ++kt) {
        const int buf = kt & 1;
        if (kt + 1 < NN / 64) {
            // stage next tile into the other buffer; prefetch tile kt+2
            *(uint4*)&Kt[buf ^ 1][skey * 72 + sc8] = kreg;
            *(uint4*)&Vt[buf ^ 1][skey * 72 + sc8] = vreg;
            int tn = (kt + 2 < NN / 64) ? kt + 2 : 0;   // clamp (dummy, L2-warm)
            kreg = *(const uint4*)(Kg + (size_t)(tn * 64 + skey) * DH + sc8);
            vreg = *(const uint4*)(Vg + (size_t)skey * NN + tn * 64 + sc8);
        }
        const unsigned short* Kc = &Kt[buf][0];
        const unsigned short* Vc = &Vt[buf][0];

        // S^T = K Q^T : D[m=key][n=qrow]; C-layout: col=qrow, regs=key
        f32x4 s[4];
        #pragma unroll
        for (int tc = 0; tc < 4; ++tc) s[tc] = (f32x4){0.f, 0.f, 0.f, 0.f};
        __builtin_amdgcn_s_setprio(1);
        #pragma unroll
        for (int tc = 0; tc < 4; ++tc) {
            #pragma unroll
            for (int kk = 0; kk < 2; ++kk) {
                short8 kf = *(const short8*)&Kc[(tc * 16 + col) * 72 + kk * 32 + quad * 8];
                s[tc] = __builtin_amdgcn_mfma_f32_16x16x32_bf16(kf, qf[kk], s[tc], 0, 0, 0);
            }
        }
        __builtin_amdgcn_s_setprio(0);

        // p = exp2(s) (scale pre-folded into Q); packed b64 write to Pt
        #pragma unroll
        for (int tc = 0; tc < 4; ++tc) {
            float p0 = expsc(s[tc][0]);
            float p1 = expsc(s[tc][1]);
            float p2 = expsc(s[tc][2]);
            float p3 = expsc(s[tc][3]);
            lsum += (p0 + p1) + (p2 + p3);
            uint2 v; v.x = cvtpk(p0, p1); v.y = cvtpk(p2, p3);
            *(uint2*)&Pt[prow + tc * 16 + quad * 4] = v;
        }

        // read P back as A-frags (same wave's rows; no barrier needed)
        short8 pf[2];
        #pragma unroll
        for (int ks = 0; ks < 2; ++ks)
            pf[ks] = *(const short8*)&Pt[prow + ks * 32 + quad * 8];

        // O += P V : A=P[m=qrow][k=key], B=V^T rows [n=dim][k=key]
        __builtin_amdgcn_s_setprio(1);
        #pragma unroll
        for (int tc = 0; tc < 4; ++tc) {
            short8 vf0 = *(const short8*)&Vc[(tc * 16 + col) * 72 + quad * 8];
            short8 vf1 = *(const short8*)&Vc[(tc * 16 + col) * 72 + 32 + quad * 8];
            accO[tc] = __builtin_amdgcn_mfma_f32_16x16x32_bf16(pf[0], vf0, accO[tc], 0, 0, 0);
            accO[tc] = __builtin_amdgcn_mfma_f32_16x16x32_bf16(pf[1], vf1, accO[tc], 0, 0, 0);
        }
        __builtin_amdgcn_s_setprio(0);

        __syncthreads();    // all waves done reading buf / writing buf^1
    }

    // reduce rowsums across quads: after this, lane holds l[qrow = lane&15]
    lsum += __shfl_xor(lsum, 16);
    lsum += __shfl_xor(lsum, 32);

    // epilogue: need l for qrow = quad*4+r
    float inv[4];
    #pragma unroll
    for (int r = 0; r < 4; ++r)
        inv[r] = 1.f / __shfl(lsum, quad * 4 + r);

    #pragma unroll
    for (int tc = 0; tc < 4; ++tc)
        #pragma unroll
        for (int r = 0; r < 4; ++r) {
            float v = accO[tc][r] * inv[r];
            Ob[(base + n0 + qbase + quad * 4 + r) * DH + tc * 16 + col] = f2b(v);
        }
}

// ---------------------------------------------------------------------------
// Output projection GEMM (unchanged this round).
// ---------------------------------------------------------------------------
__global__ __launch_bounds__(256) void out_gemm(
    const unsigned short* __restrict__ Ob,
    const unsigned short* __restrict__ wob,
    const float* __restrict__ bof,
    const uint32* __restrict__ flagp,
    void* __restrict__ outp)
{
    __shared__ unsigned short As[128 * 40];
    __shared__ unsigned short Bs[128 * 40];
    const int tid = threadIdx.x;
    const int nt = blockIdx.x >> 6, mt = blockIdx.x & 63;
    const int m0 = mt * 128, n0 = nt * 128;
    const int w = tid >> 6, lane = tid & 63, quad = lane >> 4, col = lane & 15;
    const int wr = w >> 1, wc = w & 1;
    const int fp32mode = (int)*flagp;

    f32x4 acc[4][4];
    #pragma unroll
    for (int i = 0; i < 4; ++i)
        #pragma unroll
        for (int j = 0; j < 4; ++j)
            acc[i][j] = (f32x4){0.f, 0.f, 0.f, 0.f};

    for (int kt = 0; kt < 16; ++kt) {
        int k0 = kt * 32;
        int h = k0 >> 6, koff = k0 & 63;
        __syncthreads();
        #pragma unroll
        for (int it = 0; it < 2; ++it) {
            int idx = tid + it * 256;
            int row = idx >> 2, c4 = idx & 3;
            int g = m0 + row, b = g >> 12, n = g & (NN - 1);
            *(uint4*)&As[row * 40 + c4 * 8] = *(const uint4*)(Ob +
                ((size_t)((b << 3) + h) * NN + n) * DH + koff + c4 * 8);
            *(uint4*)&Bs[row * 40 + c4 * 8] =
                *(const uint4*)(wob + (size_t)(n0 + row) * DD + k0 + c4 * 8);
        }
        __syncthreads();
        short8 wf[4], yf[4];
        #pragma unroll
        for (int i = 0; i < 4; ++i)
            wf[i] = *(const short8*)&Bs[(wr * 64 + i * 16 + col) * 40 + quad * 8];
        #pragma unroll
        for (int j = 0; j < 4; ++j)
            yf[j] = *(const short8*)&As[(wc * 64 + j * 16 + col) * 40 + quad * 8];
        #pragma unroll
        for (int i = 0; i < 4; ++i)
            #pragma unroll
            for (int j = 0; j < 4; ++j)
                acc[i][j] = __builtin_amdgcn_mfma_f32_16x16x32_bf16(
                    wf[i], yf[j], acc[i][j], 0, 0, 0);
    }

    #pragma unroll
    for (int i = 0; i < 4; ++i) {
        int e0 = n0 + wr * 64 + i * 16 + quad * 4;
        float4 bj = *(const float4*)(bof + e0);
        #pragma unroll
        for (int j = 0; j < 4; ++j) {
            int g = m0 + wc * 64 + j * 16 + col;
            float v0 = acc[i][j][0] + bj.x;
            float v1 = acc[i][j][1] + bj.y;
            float v2 = acc[i][j][2] + bj.z;
            float v3 = acc[i][j][3] + bj.w;
            if (fp32mode) {
                float4 o; o.x = v0; o.y = v1; o.z = v2; o.w = v3;
                *(float4*)((float*)outp + (size_t)g * DD + e0) = o;
            } else {
                uint2 o; o.x = pack2(v0, v1); o.y = pack2(v2, v3);
                *(uint2*)((unsigned short*)outp + (size_t)g * DD + e0) = o;
            }
        }
    }
}

// ---------------------------------------------------------------------------
extern "C" void kernel_launch(void* const* d_in, const int* in_sizes, int n_in,
                              void* d_out, int out_size, void* d_ws, size_t ws_size,
                              hipStream_t stream) {
    char* p = (char*)d_ws;
    uint32* flag = (uint32*)p;                  p += 256;
    unsigned short* xb  = (unsigned short*)p;   p += (size_t)BN * DD * 2;
    unsigned short* wsb = (unsigned short*)p;   p += (size_t)4 * DD * DD * 2;
    float*          bsf = (float*)p;            p += (size_t)4 * DD * 4;
    unsigned short* Qb  = (unsigned short*)p;   p += (size_t)PAIRS * NN * DH * 2;
    unsigned short* Kb  = (unsigned short*)p;   p += (size_t)PAIRS * NN * DH * 2;
    unsigned short* VTg = (unsigned short*)p;   p += (size_t)PAIRS * NN * DH * 2;
    unsigned short* Ob  = (unsigned short*)p;   p += (size_t)PAIRS * NN * DH * 2;

    detect_dtype<<<1, 64, 0, stream>>>((const uint32*)d_in[0], flag);
    conv_x<<<BN * DD / 2048, 256, 0, stream>>>(d_in[0], xb, flag);
    conv_w<<<512, 256, 0, stream>>>(d_in[1], d_in[3], d_in[5], d_in[7], wsb, flag);
    conv_b<<<1, 256, 0, stream>>>(d_in[2], d_in[4], d_in[6], d_in[8], bsf, flag);
    qkv_gemm<<<768, 256, 0, stream>>>(xb, wsb, bsf, Qb, Kb, VTg);
    attn_mfma<<<PAIRS * 32, 512, 0, stream>>>(Qb, Kb, VTg, Ob);
    out_gemm<<<256, 256, 0, stream>>>(Ob, wsb + (size_t)3 * DD * DD,
                                      bsf + 3 * DD, flag, d_out);
}